// Round 8
// baseline (167.314 us; speedup 1.0000x reference)
//
#include <hip/hip_runtime.h>
#include <math.h>

#define BB 8
#define TT 1024
#define SS 77

typedef short v8s __attribute__((ext_vector_type(8)));
typedef float v4f __attribute__((ext_vector_type(4)));
typedef unsigned short u16x4 __attribute__((ext_vector_type(4)));
typedef unsigned short u16x8 __attribute__((ext_vector_type(8)));
typedef unsigned short u16;

// fold 64^-0.25 * sqrt(log2 e) into q and k weights -> logits in exp2-domain
#define SCALEF 0.424660891f
#define MASKNEG (-14426.95f)   // -10000 * log2(e)

__device__ __forceinline__ u16 f2bf(float f) {
  unsigned u = __float_as_uint(f);
  u = (u + 0x7fffu + ((u >> 16) & 1u)) >> 16;
  return (u16)u;
}
__device__ __forceinline__ u16 hi16(float f) {
  return (u16)(__float_as_uint(f) >> 16);
}
__device__ __forceinline__ float bf2f(u16 u) {
  return __uint_as_float(((unsigned)u) << 16);
}
__device__ __forceinline__ void gl_lds16(const void* g, void* l) {
  __builtin_amdgcn_global_load_lds(
      (const __attribute__((address_space(1))) void*)g,
      (__attribute__((address_space(3))) void*)l, 16, 0, 0);
}

// ---------------------------------------------------------------------------
// Fused GroupNorm (blocks 0..255) + prep (blocks 256..2304).
// ---------------------------------------------------------------------------
__global__ __launch_bounds__(256) void prep_gn_kernel(
    const float* __restrict__ x, const float* __restrict__ scale,
    const float* __restrict__ bias, u16* __restrict__ nrmT,
    const float* __restrict__ qkv_w, const float* __restrict__ ekv_w,
    const float* __restrict__ proj_w, const float* __restrict__ enc,
    const float* __restrict__ qkv_b, const float* __restrict__ ekv_b,
    u16* __restrict__ wQK, u16* __restrict__ wV, u16* __restrict__ wEK,
    u16* __restrict__ wEV, u16* __restrict__ projwb, u16* __restrict__ encT,
    float* __restrict__ bQK, float* __restrict__ bV,
    float* __restrict__ bEK, float* __restrict__ bEV) {
  __shared__ u16 Xs[16 * 1024];
  __shared__ float red[8];
  int blk = blockIdx.x, tid = threadIdx.x;

  if (blk < 256) {             // ---- GroupNorm path ----
    int bg = blk;
    int b = bg >> 5, g = bg & 31;
    const float4* x4 = (const float4*)(x + (size_t)bg * 16384);
    float s = 0.f, sq = 0.f;
#pragma unroll
    for (int i = 0; i < 16; ++i) {
      int idx = tid + 256 * i;
      float4 v = x4[idx];
      s += v.x + v.y + v.z + v.w;
      sq += v.x * v.x + v.y * v.y + v.z * v.z + v.w * v.w;
      int c = idx >> 8, t4 = (idx & 255) * 4;
      u16x4 o; o.x = f2bf(v.x); o.y = f2bf(v.y); o.z = f2bf(v.z); o.w = f2bf(v.w);
      *(u16x4*)(Xs + c * 1024 + t4) = o;
    }
#pragma unroll
    for (int off = 32; off > 0; off >>= 1) {
      s += __shfl_down(s, off, 64);
      sq += __shfl_down(sq, off, 64);
    }
    int wave = tid >> 6;
    if ((tid & 63) == 0) { red[wave] = s; red[wave + 4] = sq; }
    __syncthreads();
    float ts = red[0] + red[1] + red[2] + red[3];
    float tq = red[4] + red[5] + red[6] + red[7];
    float mu = ts * (1.0f / 16384.0f);
    float var = tq * (1.0f / 16384.0f) - mu * mu;
    float rs = rsqrtf(var + 1e-5f);
    float scv[16], biv[16];
#pragma unroll
    for (int c = 0; c < 16; ++c) {
      float ss = scale[g * 16 + c] * rs;
      scv[c] = ss;
      biv[c] = bias[g * 16 + c] - mu * ss;
    }
#pragma unroll
    for (int j = 0; j < 4; ++j) {
      int t = tid + 256 * j;
      u16x8 o0, o1;
#pragma unroll
      for (int c = 0; c < 8; ++c)  o0[c] = f2bf(bf2f(Xs[c * 1024 + t]) * scv[c] + biv[c]);
#pragma unroll
      for (int c = 8; c < 16; ++c) o1[c - 8] = f2bf(bf2f(Xs[c * 1024 + t]) * scv[c] + biv[c]);
      u16* dst = nrmT + ((size_t)b * 1024 + t) * 512 + g * 16;
      *(u16x8*)dst = o0;
      *(u16x8*)(dst + 8) = o1;
    }
    return;
  }

  int p = blk - 256;           // ---- prep path ----
  if (p < 512) {               // wQK (scaled)
    int idx = p * 256 + tid;
    int n = idx >> 7, c4 = (idx & 127) * 4;
    int which = n >> 9, h = (n >> 6) & 7, ch = n & 63;
    int src = h * 192 + which * 64 + ch;
    float4 v = *(const float4*)(qkv_w + (size_t)src * 512 + c4);
    u16x4 o; o.x = f2bf(v.x * SCALEF); o.y = f2bf(v.y * SCALEF);
    o.z = f2bf(v.z * SCALEF); o.w = f2bf(v.w * SCALEF);
    *(u16x4*)(wQK + (size_t)n * 512 + c4) = o;
  } else if (p < 768) {        // wV
    int idx = (p - 512) * 256 + tid;
    int n = idx >> 7, c4 = (idx & 127) * 4;
    int h = n >> 6, ch = n & 63;
    int src = h * 192 + 128 + ch;
    float4 v = *(const float4*)(qkv_w + (size_t)src * 512 + c4);
    u16x4 o; o.x = f2bf(v.x); o.y = f2bf(v.y); o.z = f2bf(v.z); o.w = f2bf(v.w);
    *(u16x4*)(wV + (size_t)n * 512 + c4) = o;
  } else if (p < 1024) {       // wEK (scaled)
    int idx = (p - 768) * 256 + tid;
    int n = idx >> 7, c4 = (idx & 127) * 4;
    int h = n >> 6, ch = n & 63;
    int src = h * 128 + ch;
    float4 v = *(const float4*)(ekv_w + (size_t)src * 512 + c4);
    u16x4 o; o.x = f2bf(v.x * SCALEF); o.y = f2bf(v.y * SCALEF);
    o.z = f2bf(v.z * SCALEF); o.w = f2bf(v.w * SCALEF);
    *(u16x4*)(wEK + (size_t)n * 512 + c4) = o;
  } else if (p < 1280) {       // wEV
    int idx = (p - 1024) * 256 + tid;
    int n = idx >> 7, c4 = (idx & 127) * 4;
    int h = n >> 6, ch = n & 63;
    int src = h * 128 + 64 + ch;
    float4 v = *(const float4*)(ekv_w + (size_t)src * 512 + c4);
    u16x4 o; o.x = f2bf(v.x); o.y = f2bf(v.y); o.z = f2bf(v.z); o.w = f2bf(v.w);
    *(u16x4*)(wEV + (size_t)n * 512 + c4) = o;
  } else if (p < 1536) {       // projwb
    int idx = (p - 1280) * 256 + tid;
    float4 v = ((const float4*)proj_w)[idx];
    u16x4 o; o.x = f2bf(v.x); o.y = f2bf(v.y); o.z = f2bf(v.z); o.w = f2bf(v.w);
    *(u16x4*)(projwb + (size_t)idx * 4) = o;
  } else if (p < 2048) {       // encT [b][128][512], zero-padded
    int idx = (p - 1536) * 256 + tid;
    int b = idx >> 14, rem = idx & 16383;
    int s = rem >> 7, c = (rem & 127) * 4;
    u16x4 o; o.x = 0; o.y = 0; o.z = 0; o.w = 0;
    if (s < SS) {
      const float* pp = enc + ((size_t)b * 512 + c) * SS + s;
      o.x = f2bf(pp[0]); o.y = f2bf(pp[SS]); o.z = f2bf(pp[2 * SS]); o.w = f2bf(pp[3 * SS]);
    }
    *(u16x4*)(encT + ((size_t)b * 128 + s) * 512 + c) = o;
  } else {                     // biases (permuted; q/k scaled)
    for (int i = tid; i < 2560; i += 256) {
      if (i < 1024) {
        int which = i >> 9, h = (i >> 6) & 7, ch = i & 63;
        bQK[i] = qkv_b[h * 192 + which * 64 + ch] * SCALEF;
      } else if (i < 1536) {
        int j = i - 1024; int h = j >> 6, ch = j & 63;
        bV[j] = qkv_b[h * 192 + 128 + ch];
      } else if (i < 2048) {
        int j = i - 1536; int h = j >> 6, ch = j & 63;
        bEK[j] = ekv_b[h * 128 + ch] * SCALEF;
      } else {
        int j = i - 2048; int h = j >> 6, ch = j & 63;
        bEV[j] = ekv_b[h * 128 + 64 + ch];
      }
    }
  }
}

// ---------------------------------------------------------------------------
// Unified projection GEMM, DEEP pipeline: BK=32, 5 LDS buffers, prefetch
// distance 4, counted vmcnt(12) (3 future steps always in flight) -> ~1200+
// cycles of latency tolerance vs the L2-miss/L3 staging latency.
// LDS 80KB -> exactly 2 blocks/CU. XCD-colocating job swizzle + bank-free
// slot swizzle retained. Same K order -> bit-identical.
// ---------------------------------------------------------------------------
__global__ __launch_bounds__(256) void proj_all(
    const u16* __restrict__ nrmT, const u16* __restrict__ encT,
    const u16* __restrict__ wQK, const u16* __restrict__ wEK,
    const u16* __restrict__ wV, const u16* __restrict__ wEV,
    const float* __restrict__ bQK, const float* __restrict__ bEK,
    const float* __restrict__ bV, const float* __restrict__ bEV,
    u16* __restrict__ Qh, u16* __restrict__ Kfull, u16* __restrict__ Vfull) {
  __shared__ __align__(16) u16 SH[40960];   // 80KB: A 5x8KB, B 5x8KB
  u16* As = SH;                             // buf stride 4096 u16 = 8192 B
  u16* Bs = SH + 20480;

  int jj = blockIdx.x, bz = blockIdx.y;
  int job = (jj & 7) * 13 + (jj >> 3);      // XCD-colocate A-sharing jobs
  int tid = threadIdx.x;
  int lane = tid & 63, w = tid >> 6;
  int lan15 = lane & 15, quad = lane >> 4;
  int wm = w >> 1, wn = w & 1;

  int mode, m0, n0;
  const u16 *Ap, *Bp;
  const float* bias;
  u16 *dA = nullptr, *dB = nullptr;
  int TrA = 0, offA = 0, TrB = 0, offB = 0;
  int coff = 0;

  if (job < 64) {
    mode = 3; m0 = (job >> 3) * 128; n0 = (job & 7) * 128;
    Ap = nrmT + (size_t)bz * 1024 * 512; Bp = wQK; bias = bQK;
    dA = Qh; TrA = 1024; offA = 0; dB = Kfull; TrB = 1152; offB = 128;
  } else if (job < 68) {
    mode = 3; m0 = 0; n0 = (job - 64) * 128;
    Ap = encT + (size_t)bz * 128 * 512; Bp = wEK; bias = bEK;
    dA = Kfull; TrA = 1152; offA = 0; dB = Kfull; TrB = 1152; offB = 0;
  } else if (job < 100) {
    int jx = job - 68; mode = 0; m0 = (jx >> 3) * 128; n0 = (jx & 7) * 128;
    Ap = wV; Bp = nrmT + (size_t)bz * 1024 * 512; bias = bV;
    coff = 128;
  } else {
    int jx = job - 100; mode = 0; m0 = jx * 128; n0 = 0;
    Ap = wEV; Bp = encT + (size_t)bz * 128 * 512; bias = bEV;
    coff = 0;
  }

  // staging: rows of 32 bf16 (64B), 4 chunk slots; slot c of row r holds
  // global chunk c ^ fr(r), fr(r) = (r&3)^((r>>2)&3)  -> 2-way max on read
  int arow = lane >> 2;                 // 0..15
  int fr = (arow & 3) ^ ((arow >> 2) & 3);
  int achk = (lane & 3) ^ fr;
  const char* Ag = (const char*)(Ap + (size_t)(m0 + w * 32 + arow) * 512) + achk * 16;
  const char* Bg = (const char*)(Bp + (size_t)(n0 + w * 32 + arow) * 512) + achk * 16;

#define PSTAGE(s, b) do { int kb_ = (s) * 64;                                  \
    gl_lds16(Ag + kb_,         (char*)As + (b) * 8192 + w * 2048);             \
    gl_lds16(Ag + kb_ + 16384, (char*)As + (b) * 8192 + w * 2048 + 1024);      \
    gl_lds16(Bg + kb_,         (char*)Bs + (b) * 8192 + w * 2048);             \
    gl_lds16(Bg + kb_ + 16384, (char*)Bs + (b) * 8192 + w * 2048 + 1024); } while (0)

  v4f acc[4][4] = {};

  PSTAGE(0, 0);
  PSTAGE(1, 1);
  PSTAGE(2, 2);
  PSTAGE(3, 3);
  asm volatile("s_waitcnt vmcnt(12)" ::: "memory");  // step0 landed; 1-3 flying
  __builtin_amdgcn_sched_barrier(0);
  __builtin_amdgcn_s_barrier();
  __builtin_amdgcn_sched_barrier(0);

  int ch = (quad ^ (lan15 & 3) ^ ((lan15 >> 2) & 3)) * 16;
  int cur = 0;
  for (int s = 0; s < 16; ++s) {
    if (s <= 11) { int nb = cur + 4; if (nb >= 5) nb -= 5; PSTAGE(s + 4, nb); }
    const char* Ab = (const char*)As + cur * 8192;
    const char* Bb = (const char*)Bs + cur * 8192;
    v8s a[4], bf[4];
#pragma unroll
    for (int i = 0; i < 4; ++i)
      a[i] = *(const v8s*)(Ab + (wm * 64 + i * 16 + lan15) * 64 + ch);
#pragma unroll
    for (int j = 0; j < 4; ++j)
      bf[j] = *(const v8s*)(Bb + (wn * 64 + j * 16 + lan15) * 64 + ch);
    __builtin_amdgcn_s_setprio(1);
#pragma unroll
    for (int i = 0; i < 4; ++i)
#pragma unroll
      for (int j = 0; j < 4; ++j)
        acc[i][j] = __builtin_amdgcn_mfma_f32_16x16x32_bf16(a[i], bf[j], acc[i][j], 0, 0, 0);
    __builtin_amdgcn_s_setprio(0);
    if (s < 15) {
      if (s <= 11)      asm volatile("s_waitcnt vmcnt(12)" ::: "memory");
      else if (s == 12) asm volatile("s_waitcnt vmcnt(8)" ::: "memory");
      else if (s == 13) asm volatile("s_waitcnt vmcnt(4)" ::: "memory");
      else              asm volatile("s_waitcnt vmcnt(0)" ::: "memory");
      __builtin_amdgcn_sched_barrier(0);
      __builtin_amdgcn_s_barrier();
      __builtin_amdgcn_sched_barrier(0);
    }
    cur = cur + 1; if (cur == 5) cur = 0;
  }
#undef PSTAGE

  if (mode == 3) {
    u16* Tr = SH;              // [128][72]
    for (int ph = 0; ph < 2; ++ph) {
      __syncthreads();
      if (wn == ph) {
#pragma unroll
        for (int j = 0; j < 4; ++j) {
          int n = n0 + wn * 64 + j * 16 + lan15;
          float bv_ = bias[n];
#pragma unroll
          for (int i = 0; i < 4; ++i)
#pragma unroll
            for (int r = 0; r < 4; ++r)
              Tr[(wm * 64 + i * 16 + quad * 4 + r) * 72 + j * 16 + lan15] =
                  f2bf(acc[i][j][r] + bv_);
        }
      }
      __syncthreads();
      int nb = n0 + ph * 64;
      u16* dst = (nb < 512) ? dA : dB;
      int Trows = (nb < 512) ? TrA : TrB;
      int roff  = (nb < 512) ? offA : offB;
      int hh = (nb & 511) >> 6;
      int row = tid >> 1, seg = (tid & 1) * 32;
      u16* dp = dst + ((size_t)(bz * 8 + hh) * Trows + roff + m0 + row) * 64 + seg;
#pragma unroll
      for (int g = 0; g < 4; ++g)
        *(u16x8*)(dp + g * 8) = *(const u16x8*)(Tr + row * 72 + seg + g * 8);
    }
  } else {
    u16* Tr = SH;              // [128 m][72] per phase of 64 n
    u16* Cb = Vfull + (size_t)bz * 512 * 1152;
    for (int ph = 0; ph < 2; ++ph) {
      __syncthreads();
      if (wn == ph) {
#pragma unroll
        for (int i = 0; i < 4; ++i) {
          int ob = wm * 64 + i * 16 + quad * 4;
#pragma unroll
          for (int r = 0; r < 4; ++r) {
            float bi = bias[m0 + ob + r];
#pragma unroll
            for (int j = 0; j < 4; ++j)
              Tr[(ob + r) * 72 + j * 16 + lan15] = f2bf(acc[i][j][r] + bi);
          }
        }
      }
      __syncthreads();
      int row = tid >> 1, seg = (tid & 1) * 32;
      u16* dp = Cb + (size_t)(m0 + row) * 1152 + coff + n0 + ph * 64 + seg;
#pragma unroll
      for (int g = 0; g < 4; ++g)
        *(u16x8*)(dp + g * 8) = *(const u16x8*)(Tr + row * 72 + seg + g * 8);
    }
  }
}

// ---------------------------------------------------------------------------
// proj-out GEMM, deep pipeline (5 bufs, distance 4, vmcnt(9)):
// out = x + proj_w @ attn. 64x128 tiles, 512 blocks (2/CU). LDS 60KB.
// ---------------------------------------------------------------------------
__global__ __launch_bounds__(256) void proj_out(
    const u16* __restrict__ A, const u16* __restrict__ B,
    const float* __restrict__ bias, const float* __restrict__ res,
    float* __restrict__ Cf) {
  __shared__ __align__(16) u16 SH[30720];  // 60KB: As 5x4KB, Bs 5x8KB
  u16* As = SH;                            // buf stride 2048 u16 = 4096 B
  u16* Bs = SH + 10240;                    // buf stride 4096 u16 = 8192 B

  int tid = threadIdx.x;
  int lane = tid & 63, w = tid >> 6;
  int lan15 = lane & 15, quad = lane >> 4;
  int wm = w >> 1, wn = w & 1;
  int m0 = blockIdx.y * 64, n0 = blockIdx.x * 128;
  int bz = blockIdx.z;
  const u16* Bb = B + (size_t)bz * 1024 * 512;

  int arow = lane >> 2;
  int fr = (arow & 3) ^ ((arow >> 2) & 3);
  int achk = (lane & 3) ^ fr;
  const char* Ag = (const char*)(A + (size_t)(m0 + w * 16 + arow) * 512) + achk * 16;
  const char* Bg = (const char*)(Bb + (size_t)(n0 + w * 32 + arow) * 512) + achk * 16;

#define OSTAGE(s, b) do { int kb_ = (s) * 64;                                  \
    gl_lds16(Ag + kb_,         (char*)As + (b) * 4096 + w * 1024);             \
    gl_lds16(Bg + kb_,         (char*)Bs + (b) * 8192 + w * 2048);             \
    gl_lds16(Bg + kb_ + 16384, (char*)Bs + (b) * 8192 + w * 2048 + 1024); } while (0)

  v4f acc[2][4] = {};

  OSTAGE(0, 0);
  OSTAGE(1, 1);
  OSTAGE(2, 2);
  OSTAGE(3, 3);
  asm volatile("s_waitcnt vmcnt(9)" ::: "memory");
  __builtin_amdgcn_sched_barrier(0);
  __builtin_amdgcn_s_barrier();
  __builtin_amdgcn_sched_barrier(0);

  int ch = (quad ^ (lan15 & 3) ^ ((lan15 >> 2) & 3)) * 16;
  int cur = 0;
  for (int s = 0; s < 16; ++s) {
    if (s <= 11) { int nb = cur + 4; if (nb >= 5) nb -= 5; OSTAGE(s + 4, nb); }
    const char* Ab = (const char*)As + cur * 4096;
    const char* Bbuf = (const char*)Bs + cur * 8192;
    v8s a[2], bf[4];
#pragma unroll
    for (int i = 0; i < 2; ++i)
      a[i] = *(const v8s*)(Ab + (wm * 32 + i * 16 + lan15) * 64 + ch);
#pragma unroll
    for (int j = 0; j < 4; ++j)
      bf[j] = *(const v8s*)(Bbuf + (wn * 64 + j * 16 + lan15) * 64 + ch);
    __builtin_amdgcn_s_setprio(1);
#pragma unroll
    for (int i = 0; i < 2; ++i)
#pragma unroll
      for (int j = 0; j < 4; ++j)
        acc[i][j] = __builtin_amdgcn_mfma_f32_16x16x32_bf16(a[i], bf[j], acc[i][j], 0, 0, 0);
    __builtin_amdgcn_s_setprio(0);
    if (s < 15) {
      if (s <= 11)      asm volatile("s_waitcnt vmcnt(9)" ::: "memory");
      else if (s == 12) asm volatile("s_waitcnt vmcnt(6)" ::: "memory");
      else if (s == 13) asm volatile("s_waitcnt vmcnt(3)" ::: "memory");
      else              asm volatile("s_waitcnt vmcnt(0)" ::: "memory");
      __builtin_amdgcn_sched_barrier(0);
      __builtin_amdgcn_s_barrier();
      __builtin_amdgcn_sched_barrier(0);
    }
    cur = cur + 1; if (cur == 5) cur = 0;
  }
#undef OSTAGE

  const float* rb = res + (size_t)bz * 512 * 1024;
  float* Cb = Cf + (size_t)bz * 512 * 1024;
#pragma unroll
  for (int i = 0; i < 2; ++i) {
    int ob = m0 + wm * 32 + i * 16 + quad * 4;
#pragma unroll
    for (int r = 0; r < 4; ++r) {
      int o = ob + r;
      float bi = bias[o];
#pragma unroll
      for (int j = 0; j < 4; ++j) {
        int n = n0 + wn * 64 + j * 16 + lan15;
        Cb[(size_t)o * 1024 + n] = acc[i][j][r] + bi + rb[(size_t)o * 1024 + n];
      }
    }
  }
}

// ---------------------------------------------------------------------------
// MFMA flash attention v4 (verified): S^T-form QK (swapped MFMA operands),
// fixed-max exp2 softmax, b64-packed P stores, per-lane l.
// Block = 4 waves x 32 t; grid (64 bh, 8). K/V double-buffered, 1 barrier.
// ---------------------------------------------------------------------------
#define AOFF_K 0           // 2 x 8192
#define AOFF_V 16384       // 2 x 8192
#define AOFF_P 32768       // 4 waves x 4608 (Q overlay + P [32][72])
#define AOFF_AM 51200      // 128 f32 (mask, then reused for l-sums)
#define ASMEM  51712

__global__ __launch_bounds__(256) void attn_kernel(
    const u16* __restrict__ Qh, const u16* __restrict__ Kf,
    const u16* __restrict__ Vf, const int* __restrict__ mask,
    u16* __restrict__ attnT) {
  __shared__ __align__(16) unsigned char smem[ASMEM];
  float* AM = (float*)(smem + AOFF_AM);

  int bh = blockIdx.x, b = bh >> 3, h = bh & 7;
  int t0 = blockIdx.y * 128;
  int tid = threadIdx.x;
  int lane = tid & 63, w = tid >> 6;
  int lan15 = lane & 15, quad = lane >> 4;
  int r8 = lane >> 3, c8 = lane & 7;
  int swE = (c8 ^ r8) * 8;

  const u16* Qb = Qh + (size_t)bh * 1024 * 64;
  const u16* Kb = Kf + (size_t)bh * 1152 * 64;
  const u16* Vb = Vf + (size_t)bh * 64 * 1152;
  char* Pw = (char*)smem + AOFF_P + w * 4608;
  u16* Pu = (u16*)Pw;

  if (tid < 128)
    AM[tid] = (tid < SS) ? ((mask[h * SS + tid] != 0) ? 0.f : MASKNEG) : -1e30f;

  // stage Q (wave-private region, overwritten by P later) + chunk 0 K/V
#pragma unroll
  for (int i = 0; i < 4; ++i)
    gl_lds16(Qb + (size_t)(t0 + w * 32 + i * 8 + r8) * 64 + swE, Pw + i * 1024);
#pragma unroll
  for (int i = 0; i < 2; ++i) {
    int row = w * 16 + i * 8;
    gl_lds16(Kb + (size_t)(row + r8) * 64 + swE, (char*)smem + AOFF_K + row * 128);
    gl_lds16(Vb + (size_t)(row + r8) * 1152 + swE, (char*)smem + AOFF_V + row * 128);
  }
  __syncthreads();

  // hoist Q fragments (used as MFMA B-operand: B[k=ch][n=t], t=lan15)
  v8s aq[2][2];
#pragma unroll
  for (int mt = 0; mt < 2; ++mt)
#pragma unroll
    for (int ks = 0; ks < 2; ++ks)
      aq[mt][ks] = *(const v8s*)(Pw + (mt * 16 + lan15) * 128 +
                                 (((ks * 4 + quad) ^ (lan15 & 7)) * 16));

  v4f O[2][4] = {};
  float lsum[2] = {0.f, 0.f};   // per-lane: all 16 chunk values share t=lan15

  for (int c = 0; c < 18; ++c) {
    int cur = c & 1;
    if (c < 17) {
      int nb = cur ^ 1;
#pragma unroll
      for (int i = 0; i < 2; ++i) {
        int row = w * 16 + i * 8;
        gl_lds16(Kb + (size_t)((c + 1) * 64 + row + r8) * 64 + swE,
                 (char*)smem + AOFF_K + nb * 8192 + row * 128);
        gl_lds16(Vb + (size_t)(row + r8) * 1152 + (c + 1) * 64 + swE,
                 (char*)smem + AOFF_V + nb * 8192 + row * 128);
      }
    }
    const char* Kc = (const char*)smem + AOFF_K + cur * 8192;
    const char* Vc = (const char*)smem + AOFF_V + cur * 8192;

    // QK^T transposed: ST[nt][mt], rows = s (quad*4+r), cols = t (lan15)
    v4f ST[4][2] = {};
#pragma unroll
    for (int ks = 0; ks < 2; ++ks) {
      int cofs = ((ks * 4 + quad) ^ (lan15 & 7)) * 16;
      v8s bk[4];
#pragma unroll
      for (int nt = 0; nt < 4; ++nt)
        bk[nt] = *(const v8s*)(Kc + (nt * 16 + lan15) * 128 + cofs);
#pragma unroll
      for (int nt = 0; nt < 4; ++nt)
#pragma unroll
        for (int mt = 0; mt < 2; ++mt)
          ST[nt][mt] = __builtin_amdgcn_mfma_f32_16x16x32_bf16(bk[nt], aq[mt][ks], ST[nt][mt], 0, 0, 0);
    }

    // mask add (enc chunks only): s = c*64 + nt*16 + quad*4 + r
    if (c < 2) {
#pragma unroll
      for (int nt = 0; nt < 4; ++nt)
#pragma unroll
        for (int r = 0; r < 4; ++r) {
          float a_ = AM[c * 64 + nt * 16 + quad * 4 + r];
#pragma unroll
          for (int mt = 0; mt < 2; ++mt) ST[nt][mt][r] += a_;
        }
    }

    // exp2 + b64-packed P store: Pu[(t)*72 + nt*16 + quad*4] = {e0..e3}
#pragma unroll
    for (int mt = 0; mt < 2; ++mt) {
#pragma unroll
      for (int nt = 0; nt < 4; ++nt) {
        float e0 = __builtin_amdgcn_exp2f(ST[nt][mt][0]);
        float e1 = __builtin_amdgcn_exp2f(ST[nt][mt][1]);
        float e2 = __builtin_amdgcn_exp2f(ST[nt][mt][2]);
        float e3 = __builtin_amdgcn_exp2f(ST[nt][mt][3]);
        u16x4 pk; pk.x = hi16(e0); pk.y = hi16(e1); pk.z = hi16(e2); pk.w = hi16(e3);
        *(u16x4*)&Pu[(mt * 16 + lan15) * 72 + nt * 16 + quad * 4] = pk;
        lsum[mt] += (e0 + e1) + (e2 + e3);
      }
    }

    // PV: O[t][c] += P[t][s] V^T[s][c]
#pragma unroll
    for (int ks = 0; ks < 2; ++ks) {
      int cofs = ((ks * 4 + quad) ^ (lan15 & 7)) * 16;
      v8s ap[2], bv[4];
#pragma unroll
      for (int mt = 0; mt < 2; ++mt)
        ap[mt] = *(const v8s*)(Pw + (mt * 16 + lan15) * 144 + ks * 64 + quad * 16);
#pragma unroll
      for (int nc = 0; nc < 4; ++nc)
        bv[nc] = *(const v8s*)(Vc + (nc * 16 + lan15) * 128 + cofs);
#pragma unroll
      for (int mt = 0; mt < 2; ++mt)
#pragma unroll
        for (int nc = 0; nc < 4; ++nc)
          O[mt][nc] = __builtin_amdgcn_mfma_f32_16x16x32_bf16(ap[mt], bv[nc], O[mt][nc], 0, 0, 0);
    }
    __syncthreads();
  }

  // l: reduce across quads (t=lan15), bounce through LDS to (quad*4+r) index
#pragma unroll
  for (int mt = 0; mt < 2; ++mt) {
    float v = lsum[mt];
    v += __shfl_xor(v, 16, 64);
    v += __shfl_xor(v, 32, 64);
    AM[w * 32 + mt * 16 + lan15] = v;   // 4 quads write identical value
  }
  __syncthreads();
  float inv[2][4];
#pragma unroll
  for (int mt = 0; mt < 2; ++mt)
#pragma unroll
    for (int r = 0; r < 4; ++r)
      inv[mt][r] = 1.0f / AM[w * 32 + mt * 16 + quad * 4 + r];

  float* Ot = (float*)smem;
#pragma unroll
  for (int mt = 0; mt < 2; ++mt)
#pragma unroll
    for (int nc = 0; nc < 4; ++nc)
#pragma unroll
      for (int r = 0; r < 4; ++r)
        Ot[(w * 32 + mt * 16 + quad * 4 + r) * 68 + nc * 16 + lan15] =
            O[mt][nc][r] * inv[mt][r];
  __syncthreads();
  {
    int row = tid >> 1, seg = (tid & 1) * 32;
    const float* src = Ot + row * 68 + seg;
    u16* dp = attnT + ((size_t)b * 1024 + t0 + row) * 512 + h * 64 + seg;
#pragma unroll
    for (int g = 0; g < 4; ++g) {
      u16x8 o;
#pragma unroll
      for (int k = 0; k < 8; ++k) o[k] = f2bf(src[g * 8 + k]);
      *(u16x8*)(dp + g * 8) = o;
    }
  }
}

// ---------------------------------------------------------------------------
extern "C" void kernel_launch(void* const* d_in, const int* in_sizes, int n_in,
                              void* d_out, int out_size, void* d_ws, size_t ws_size,
                              hipStream_t stream) {
  const float* x       = (const float*)d_in[0];
  const float* enc     = (const float*)d_in[1];
  const int*   mask    = (const int*)d_in[2];
  const float* nscale  = (const float*)d_in[3];
  const float* nbias   = (const float*)d_in[4];
  const float* qkv_w   = (const float*)d_in[5];
  const float* qkv_b   = (const float*)d_in[6];
  const float* ekv_w   = (const float*)d_in[7];
  const float* ekv_b   = (const float*)d_in[8];
  const float* proj_w  = (const float*)d_in[9];
  const float* proj_b  = (const float*)d_in[10];
  float* out = (float*)d_out;

  char* ws = (char*)d_ws;
  const size_t MiB = 1048576;
  u16* nrmT   = (u16*)(ws);                        // 8 MiB  [8][1024][512]
  u16* Qh     = (u16*)(ws + 8 * MiB);              // 8 MiB  [64][1024][64]
  u16* Kfull  = (u16*)(ws + 16 * MiB);             // 9.4 MiB [64][1152][64]
  u16* Vfull  = (u16*)(ws + 26 * MiB);             // 9.4 MiB [64][64][1152]
  u16* attnT  = (u16*)(ws + 36 * MiB);             // 8 MiB  [8][1024][512]
  u16* encT   = (u16*)(ws + 44 * MiB);             // 1 MiB  [8][128][512]
  u16* wQK    = (u16*)(ws + 45 * MiB);             // 1 MiB
  u16* wV     = (u16*)(ws + 46 * MiB);             // 0.5 MiB
  u16* wEK    = (u16*)(ws + 46 * MiB + 524288);
  u16* wEV    = (u16*)(ws + 47 * MiB);
  u16* projwb = (u16*)(ws + 47 * MiB + 524288);
  float* bQK  = (float*)(ws + 48 * MiB);
  float* bV   = (float*)(ws + 48 * MiB + 4096);
  float* bEK  = (float*)(ws + 48 * MiB + 6144);
  float* bEV  = (float*)(ws + 48 * MiB + 8192);

  // 1) fused GroupNorm + prep
  prep_gn_kernel<<<dim3(2305), dim3(256), 0, stream>>>(
      x, nscale, nbias, nrmT, qkv_w, ekv_w, proj_w, enc, qkv_b, ekv_b,
      wQK, wV, wEK, wEV, projwb, encT, bQK, bV, bEK, bEV);

  // 2) ALL projections (QK + EK + V + EV) in one launch
  proj_all<<<dim3(104, BB), dim3(256), 0, stream>>>(
      nrmT, encT, wQK, wEK, wV, wEV, bQK, bEK, bV, bEV, Qh, Kfull, Vfull);

  // 3) attention -> attnT [8][1024][512]
  attn_kernel<<<dim3(64, 8), dim3(256), 0, stream>>>(
      Qh, Kfull, Vfull, mask, attnT);

  // 4) out = x + proj_w @ attn (64x128 tiles, 512 blocks = 2/CU)
  proj_out<<<dim3(8, 8, BB), dim3(256), 0, stream>>>(
      projwb, attnT, proj_b, x, out);
}

// Round 9
// 160.451 us; speedup vs baseline: 1.0428x; 1.0428x over previous
//
#include <hip/hip_runtime.h>
#include <math.h>

#define BB 8
#define TT 1024
#define SS 77

typedef short v8s __attribute__((ext_vector_type(8)));
typedef float v4f __attribute__((ext_vector_type(4)));
typedef unsigned short u16x4 __attribute__((ext_vector_type(4)));
typedef unsigned short u16x8 __attribute__((ext_vector_type(8)));
typedef unsigned short u16;

// fold 64^-0.25 * sqrt(log2 e) into q and k weights -> logits in exp2-domain
#define SCALEF 0.424660891f
#define MASKNEG (-14426.95f)   // -10000 * log2(e)

// chunk-slot swizzle within each 32-elem (4x16B) row group of the K-blocked
// layout [kstep][row][32]: chunk c of row r stored at slot c ^ FR(r).
#define FR(r) ((((r) & 3) ^ (((r) >> 2) & 3)))

__device__ __forceinline__ u16 f2bf(float f) {
  unsigned u = __float_as_uint(f);
  u = (u + 0x7fffu + ((u >> 16) & 1u)) >> 16;
  return (u16)u;
}
__device__ __forceinline__ u16 hi16(float f) {
  return (u16)(__float_as_uint(f) >> 16);
}
__device__ __forceinline__ float bf2f(u16 u) {
  return __uint_as_float(((unsigned)u) << 16);
}
__device__ __forceinline__ void gl_lds16(const void* g, void* l) {
  __builtin_amdgcn_global_load_lds(
      (const __attribute__((address_space(1))) void*)g,
      (__attribute__((address_space(3))) void*)l, 16, 0, 0);
}

// ---------------------------------------------------------------------------
// Fused GroupNorm (blocks 0..255) + prep (blocks 256..2304).
// All GEMM operands written in K-blocked swizzled layout [kstep][row][32].
// ---------------------------------------------------------------------------
__global__ __launch_bounds__(256) void prep_gn_kernel(
    const float* __restrict__ x, const float* __restrict__ scale,
    const float* __restrict__ bias, u16* __restrict__ nrmT,
    const float* __restrict__ qkv_w, const float* __restrict__ ekv_w,
    const float* __restrict__ proj_w, const float* __restrict__ enc,
    const float* __restrict__ qkv_b, const float* __restrict__ ekv_b,
    u16* __restrict__ wQK, u16* __restrict__ wV, u16* __restrict__ wEK,
    u16* __restrict__ wEV, u16* __restrict__ projwb, u16* __restrict__ encT,
    float* __restrict__ bQK, float* __restrict__ bV,
    float* __restrict__ bEK, float* __restrict__ bEV) {
  __shared__ u16 Xs[16 * 1024];
  __shared__ float red[8];
  int blk = blockIdx.x, tid = threadIdx.x;

  if (blk < 256) {             // ---- GroupNorm path ----
    int bg = blk;
    int b = bg >> 5, g = bg & 31;
    const float4* x4 = (const float4*)(x + (size_t)bg * 16384);
    float s = 0.f, sq = 0.f;
#pragma unroll
    for (int i = 0; i < 16; ++i) {
      int idx = tid + 256 * i;
      float4 v = x4[idx];
      s += v.x + v.y + v.z + v.w;
      sq += v.x * v.x + v.y * v.y + v.z * v.z + v.w * v.w;
      int c = idx >> 8, t4 = (idx & 255) * 4;
      u16x4 o; o.x = f2bf(v.x); o.y = f2bf(v.y); o.z = f2bf(v.z); o.w = f2bf(v.w);
      *(u16x4*)(Xs + c * 1024 + t4) = o;
    }
#pragma unroll
    for (int off = 32; off > 0; off >>= 1) {
      s += __shfl_down(s, off, 64);
      sq += __shfl_down(sq, off, 64);
    }
    int wave = tid >> 6;
    if ((tid & 63) == 0) { red[wave] = s; red[wave + 4] = sq; }
    __syncthreads();
    float ts = red[0] + red[1] + red[2] + red[3];
    float tq = red[4] + red[5] + red[6] + red[7];
    float mu = ts * (1.0f / 16384.0f);
    float var = tq * (1.0f / 16384.0f) - mu * mu;
    float rs = rsqrtf(var + 1e-5f);
    float scv[16], biv[16];
#pragma unroll
    for (int c = 0; c < 16; ++c) {
      float ss = scale[g * 16 + c] * rs;
      scv[c] = ss;
      biv[c] = bias[g * 16 + c] - mu * ss;
    }
#pragma unroll
    for (int j = 0; j < 4; ++j) {
      int t = tid + 256 * j;
      u16x8 o0, o1;
#pragma unroll
      for (int c = 0; c < 8; ++c)  o0[c] = f2bf(bf2f(Xs[c * 1024 + t]) * scv[c] + biv[c]);
#pragma unroll
      for (int c = 8; c < 16; ++c) o1[c - 8] = f2bf(bf2f(Xs[c * 1024 + t]) * scv[c] + biv[c]);
      // channels g*16..g*16+15 -> kstep g>>1, chunks (g&1)*2, (g&1)*2+1
      int frt = FR(t);
      u16* dst = nrmT + (((size_t)b * 16 + (g >> 1)) * 1024 + t) * 32;
      *(u16x8*)(dst + ((((g & 1) * 2) ^ frt) * 8)) = o0;
      *(u16x8*)(dst + ((((g & 1) * 2 + 1) ^ frt) * 8)) = o1;
    }
    return;
  }

  int p = blk - 256;           // ---- prep path ----
  if (p < 512) {               // wQK (scaled) [16][1024][32]
    int idx = p * 256 + tid;
    int n = idx >> 7, c4 = (idx & 127) * 4;
    int which = n >> 9, h = (n >> 6) & 7, ch = n & 63;
    int src = h * 192 + which * 64 + ch;
    float4 v = *(const float4*)(qkv_w + (size_t)src * 512 + c4);
    u16x4 o; o.x = f2bf(v.x * SCALEF); o.y = f2bf(v.y * SCALEF);
    o.z = f2bf(v.z * SCALEF); o.w = f2bf(v.w * SCALEF);
    int sl = ((((c4 & 31) >> 3) ^ FR(n)) * 8) + (c4 & 7);
    *(u16x4*)(wQK + ((size_t)(c4 >> 5) * 1024 + n) * 32 + sl) = o;
  } else if (p < 768) {        // wV [16][512][32]
    int idx = (p - 512) * 256 + tid;
    int n = idx >> 7, c4 = (idx & 127) * 4;
    int h = n >> 6, ch = n & 63;
    int src = h * 192 + 128 + ch;
    float4 v = *(const float4*)(qkv_w + (size_t)src * 512 + c4);
    u16x4 o; o.x = f2bf(v.x); o.y = f2bf(v.y); o.z = f2bf(v.z); o.w = f2bf(v.w);
    int sl = ((((c4 & 31) >> 3) ^ FR(n)) * 8) + (c4 & 7);
    *(u16x4*)(wV + ((size_t)(c4 >> 5) * 512 + n) * 32 + sl) = o;
  } else if (p < 1024) {       // wEK (scaled) [16][512][32]
    int idx = (p - 768) * 256 + tid;
    int n = idx >> 7, c4 = (idx & 127) * 4;
    int h = n >> 6, ch = n & 63;
    int src = h * 128 + ch;
    float4 v = *(const float4*)(ekv_w + (size_t)src * 512 + c4);
    u16x4 o; o.x = f2bf(v.x * SCALEF); o.y = f2bf(v.y * SCALEF);
    o.z = f2bf(v.z * SCALEF); o.w = f2bf(v.w * SCALEF);
    int sl = ((((c4 & 31) >> 3) ^ FR(n)) * 8) + (c4 & 7);
    *(u16x4*)(wEK + ((size_t)(c4 >> 5) * 512 + n) * 32 + sl) = o;
  } else if (p < 1280) {       // wEV [16][512][32]
    int idx = (p - 1024) * 256 + tid;
    int n = idx >> 7, c4 = (idx & 127) * 4;
    int h = n >> 6, ch = n & 63;
    int src = h * 128 + 64 + ch;
    float4 v = *(const float4*)(ekv_w + (size_t)src * 512 + c4);
    u16x4 o; o.x = f2bf(v.x); o.y = f2bf(v.y); o.z = f2bf(v.z); o.w = f2bf(v.w);
    int sl = ((((c4 & 31) >> 3) ^ FR(n)) * 8) + (c4 & 7);
    *(u16x4*)(wEV + ((size_t)(c4 >> 5) * 512 + n) * 32 + sl) = o;
  } else if (p < 1536) {       // projwb [16][512][32]
    int idx = (p - 1280) * 256 + tid;
    int row = idx >> 7, c4 = (idx & 127) * 4;
    float4 v = *(const float4*)(proj_w + (size_t)row * 512 + c4);
    u16x4 o; o.x = f2bf(v.x); o.y = f2bf(v.y); o.z = f2bf(v.z); o.w = f2bf(v.w);
    int sl = ((((c4 & 31) >> 3) ^ FR(row)) * 8) + (c4 & 7);
    *(u16x4*)(projwb + ((size_t)(c4 >> 5) * 512 + row) * 32 + sl) = o;
  } else if (p < 2048) {       // encT [b][16][128][32], zero-padded
    int idx = (p - 1536) * 256 + tid;
    int b = idx >> 14, rem = idx & 16383;
    int s = rem >> 7, c = (rem & 127) * 4;
    u16x4 o; o.x = 0; o.y = 0; o.z = 0; o.w = 0;
    if (s < SS) {
      const float* pp = enc + ((size_t)b * 512 + c) * SS + s;
      o.x = f2bf(pp[0]); o.y = f2bf(pp[SS]); o.z = f2bf(pp[2 * SS]); o.w = f2bf(pp[3 * SS]);
    }
    int sl = ((((c & 31) >> 3) ^ FR(s)) * 8) + (c & 7);
    *(u16x4*)(encT + (((size_t)b * 16 + (c >> 5)) * 128 + s) * 32 + sl) = o;
  } else {                     // biases (permuted; q/k scaled)
    for (int i = tid; i < 2560; i += 256) {
      if (i < 1024) {
        int which = i >> 9, h = (i >> 6) & 7, ch = i & 63;
        bQK[i] = qkv_b[h * 192 + which * 64 + ch] * SCALEF;
      } else if (i < 1536) {
        int j = i - 1024; int h = j >> 6, ch = j & 63;
        bV[j] = qkv_b[h * 192 + 128 + ch];
      } else if (i < 2048) {
        int j = i - 1536; int h = j >> 6, ch = j & 63;
        bEK[j] = ekv_b[h * 128 + ch] * SCALEF;
      } else {
        int j = i - 2048; int h = j >> 6, ch = j & 63;
        bEV[j] = ekv_b[h * 128 + 64 + ch];
      }
    }
  }
}

// ---------------------------------------------------------------------------
// Unified projection GEMM: K-blocked operands -> each step's 128x32 tile is
// ONE contiguous 8KB read (2 x 1KB gl_lds16 per wave per matrix, perfectly
// coalesced). Triple-buffered, distance-2, counted vmcnt. LDS 48KB (3/CU).
// Bank swizzle lives in the stored layout (FR). Same K order -> bit-identical.
// ---------------------------------------------------------------------------
__global__ __launch_bounds__(256) void proj_all(
    const u16* __restrict__ nrmT, const u16* __restrict__ encT,
    const u16* __restrict__ wQK, const u16* __restrict__ wEK,
    const u16* __restrict__ wV, const u16* __restrict__ wEV,
    const float* __restrict__ bQK, const float* __restrict__ bEK,
    const float* __restrict__ bV, const float* __restrict__ bEV,
    u16* __restrict__ Qh, u16* __restrict__ Kfull, u16* __restrict__ Vfull) {
  __shared__ __align__(16) u16 SH[24576];   // 48KB: A 3x8KB, B 3x8KB
  u16* As = SH;                             // buf stride 4096 u16 = 8192 B
  u16* Bs = SH + 12288;

  int jj = blockIdx.x, bz = blockIdx.y;
  int job = (jj & 7) * 13 + (jj >> 3);      // XCD-colocate A-sharing jobs
  int tid = threadIdx.x;
  int lane = tid & 63, w = tid >> 6;
  int lan15 = lane & 15, quad = lane >> 4;
  int wm = w >> 1, wn = w & 1;

  int mode, m0, n0, RA, RB;
  const u16 *Ap, *Bp;
  const float* bias;
  u16 *dA = nullptr, *dB = nullptr;
  int TrA = 0, offA = 0, TrB = 0, offB = 0;
  int coff = 0;

  if (job < 64) {
    mode = 3; m0 = (job >> 3) * 128; n0 = (job & 7) * 128;
    Ap = nrmT + (size_t)bz * 524288; RA = 1024; Bp = wQK; RB = 1024; bias = bQK;
    dA = Qh; TrA = 1024; offA = 0; dB = Kfull; TrB = 1152; offB = 128;
  } else if (job < 68) {
    mode = 3; m0 = 0; n0 = (job - 64) * 128;
    Ap = encT + (size_t)bz * 65536; RA = 128; Bp = wEK; RB = 512; bias = bEK;
    dA = Kfull; TrA = 1152; offA = 0; dB = Kfull; TrB = 1152; offB = 0;
  } else if (job < 100) {
    int jx = job - 68; mode = 0; m0 = (jx >> 3) * 128; n0 = (jx & 7) * 128;
    Ap = wV; RA = 512; Bp = nrmT + (size_t)bz * 524288; RB = 1024; bias = bV;
    coff = 128;
  } else {
    int jx = job - 100; mode = 0; m0 = jx * 128; n0 = 0;
    Ap = wEV; RA = 512; Bp = encT + (size_t)bz * 65536; RB = 128; bias = bEV;
    coff = 0;
  }

  // contiguous staging: wave w covers rows base+w*32..+31 (2KB = 2 x 1KB)
  const char* Ag = (const char*)Ap + ((size_t)(m0 + w * 32) * 64) + lane * 16;
  const char* Bg = (const char*)Bp + ((size_t)(n0 + w * 32) * 64) + lane * 16;
  size_t astr = (size_t)RA * 64, bstr = (size_t)RB * 64;

#define PSTAGE(s, b) do {                                                      \
    gl_lds16(Ag + (size_t)(s) * astr,        (char*)As + (b) * 8192 + w * 2048);\
    gl_lds16(Ag + (size_t)(s) * astr + 1024, (char*)As + (b) * 8192 + w * 2048 + 1024);\
    gl_lds16(Bg + (size_t)(s) * bstr,        (char*)Bs + (b) * 8192 + w * 2048);\
    gl_lds16(Bg + (size_t)(s) * bstr + 1024, (char*)Bs + (b) * 8192 + w * 2048 + 1024); } while (0)

  v4f acc[4][4] = {};

  PSTAGE(0, 0);
  PSTAGE(1, 1);
  asm volatile("s_waitcnt vmcnt(4)" ::: "memory");   // step0 landed; step1 flying
  __builtin_amdgcn_sched_barrier(0);
  __builtin_amdgcn_s_barrier();
  __builtin_amdgcn_sched_barrier(0);

  int ch = (quad ^ FR(lan15)) * 16;
  int cur = 0;
  for (int s = 0; s < 16; ++s) {
    if (s <= 13) { int nb = cur + 2; if (nb >= 3) nb -= 3; PSTAGE(s + 2, nb); }
    const char* Ab = (const char*)As + cur * 8192;
    const char* Bb = (const char*)Bs + cur * 8192;
    v8s a[4], bf[4];
#pragma unroll
    for (int i = 0; i < 4; ++i)
      a[i] = *(const v8s*)(Ab + (wm * 64 + i * 16 + lan15) * 64 + ch);
#pragma unroll
    for (int j = 0; j < 4; ++j)
      bf[j] = *(const v8s*)(Bb + (wn * 64 + j * 16 + lan15) * 64 + ch);
    __builtin_amdgcn_s_setprio(1);
#pragma unroll
    for (int i = 0; i < 4; ++i)
#pragma unroll
      for (int j = 0; j < 4; ++j)
        acc[i][j] = __builtin_amdgcn_mfma_f32_16x16x32_bf16(a[i], bf[j], acc[i][j], 0, 0, 0);
    __builtin_amdgcn_s_setprio(0);
    if (s < 15) {
      if (s <= 13) asm volatile("s_waitcnt vmcnt(4)" ::: "memory");
      else         asm volatile("s_waitcnt vmcnt(0)" ::: "memory");
      __builtin_amdgcn_sched_barrier(0);
      __builtin_amdgcn_s_barrier();
      __builtin_amdgcn_sched_barrier(0);
    }
    cur = cur + 1; if (cur == 3) cur = 0;
  }
#undef PSTAGE

  if (mode == 3) {
    u16* Tr = SH;              // [128][72]
    for (int ph = 0; ph < 2; ++ph) {
      __syncthreads();
      if (wn == ph) {
#pragma unroll
        for (int j = 0; j < 4; ++j) {
          int n = n0 + wn * 64 + j * 16 + lan15;
          float bv_ = bias[n];
#pragma unroll
          for (int i = 0; i < 4; ++i)
#pragma unroll
            for (int r = 0; r < 4; ++r)
              Tr[(wm * 64 + i * 16 + quad * 4 + r) * 72 + j * 16 + lan15] =
                  f2bf(acc[i][j][r] + bv_);
        }
      }
      __syncthreads();
      int nb = n0 + ph * 64;
      u16* dst = (nb < 512) ? dA : dB;
      int Trows = (nb < 512) ? TrA : TrB;
      int roff  = (nb < 512) ? offA : offB;
      int hh = (nb & 511) >> 6;
      int row = tid >> 1, seg = (tid & 1) * 32;
      u16* dp = dst + ((size_t)(bz * 8 + hh) * Trows + roff + m0 + row) * 64 + seg;
#pragma unroll
      for (int g = 0; g < 4; ++g)
        *(u16x8*)(dp + g * 8) = *(const u16x8*)(Tr + row * 72 + seg + g * 8);
    }
  } else {
    u16* Tr = SH;              // [128 m][72] per phase of 64 n
    u16* Cb = Vfull + (size_t)bz * 512 * 1152;
    for (int ph = 0; ph < 2; ++ph) {
      __syncthreads();
      if (wn == ph) {
#pragma unroll
        for (int i = 0; i < 4; ++i) {
          int ob = wm * 64 + i * 16 + quad * 4;
#pragma unroll
          for (int r = 0; r < 4; ++r) {
            float bi = bias[m0 + ob + r];
#pragma unroll
            for (int j = 0; j < 4; ++j)
              Tr[(ob + r) * 72 + j * 16 + lan15] = f2bf(acc[i][j][r] + bi);
          }
        }
      }
      __syncthreads();
      int row = tid >> 1, seg = (tid & 1) * 32;
      u16* dp = Cb + (size_t)(m0 + row) * 1152 + coff + n0 + ph * 64 + seg;
#pragma unroll
      for (int g = 0; g < 4; ++g)
        *(u16x8*)(dp + g * 8) = *(const u16x8*)(Tr + row * 72 + seg + g * 8);
    }
  }
}

// ---------------------------------------------------------------------------
// proj-out GEMM: K-blocked coalesced staging, triple-buffer distance-2.
// out = x + proj_w @ attn. 64x128 tiles, 512 blocks. LDS 36KB.
// ---------------------------------------------------------------------------
__global__ __launch_bounds__(256) void proj_out(
    const u16* __restrict__ A, const u16* __restrict__ B,
    const float* __restrict__ bias, const float* __restrict__ res,
    float* __restrict__ Cf) {
  __shared__ __align__(16) u16 SH[18432];  // 36KB: As 3x4KB, Bs 3x8KB
  u16* As = SH;                            // buf stride 2048 u16 = 4096 B
  u16* Bs = SH + 6144;                     // buf stride 4096 u16 = 8192 B

  int tid = threadIdx.x;
  int lane = tid & 63, w = tid >> 6;
  int lan15 = lane & 15, quad = lane >> 4;
  int wm = w >> 1, wn = w & 1;
  int m0 = blockIdx.y * 64, n0 = blockIdx.x * 128;
  int bz = blockIdx.z;
  const u16* Bb = B + (size_t)bz * 524288;   // [16][1024][32]

  const char* Ag = (const char*)A + ((size_t)(m0 + w * 16) * 64) + lane * 16;
  const char* Bg = (const char*)Bb + ((size_t)(n0 + w * 32) * 64) + lane * 16;
  const size_t astr = 512 * 64, bstr = 1024 * 64;

#define OSTAGE(s, b) do {                                                      \
    gl_lds16(Ag + (size_t)(s) * astr,        (char*)As + (b) * 4096 + w * 1024);\
    gl_lds16(Bg + (size_t)(s) * bstr,        (char*)Bs + (b) * 8192 + w * 2048);\
    gl_lds16(Bg + (size_t)(s) * bstr + 1024, (char*)Bs + (b) * 8192 + w * 2048 + 1024); } while (0)

  v4f acc[2][4] = {};

  OSTAGE(0, 0);
  OSTAGE(1, 1);
  asm volatile("s_waitcnt vmcnt(3)" ::: "memory");
  __builtin_amdgcn_sched_barrier(0);
  __builtin_amdgcn_s_barrier();
  __builtin_amdgcn_sched_barrier(0);

  int ch = (quad ^ FR(lan15)) * 16;
  int cur = 0;
  for (int s = 0; s < 16; ++s) {
    if (s <= 13) { int nb = cur + 2; if (nb >= 3) nb -= 3; OSTAGE(s + 2, nb); }
    const char* Ab = (const char*)As + cur * 4096;
    const char* Bbuf = (const char*)Bs + cur * 8192;
    v8s a[2], bf[4];
#pragma unroll
    for (int i = 0; i < 2; ++i)
      a[i] = *(const v8s*)(Ab + (wm * 32 + i * 16 + lan15) * 64 + ch);
#pragma unroll
    for (int j = 0; j < 4; ++j)
      bf[j] = *(const v8s*)(Bbuf + (wn * 64 + j * 16 + lan15) * 64 + ch);
    __builtin_amdgcn_s_setprio(1);
#pragma unroll
    for (int i = 0; i < 2; ++i)
#pragma unroll
      for (int j = 0; j < 4; ++j)
        acc[i][j] = __builtin_amdgcn_mfma_f32_16x16x32_bf16(a[i], bf[j], acc[i][j], 0, 0, 0);
    __builtin_amdgcn_s_setprio(0);
    if (s < 15) {
      if (s <= 13) asm volatile("s_waitcnt vmcnt(3)" ::: "memory");
      else         asm volatile("s_waitcnt vmcnt(0)" ::: "memory");
      __builtin_amdgcn_sched_barrier(0);
      __builtin_amdgcn_s_barrier();
      __builtin_amdgcn_sched_barrier(0);
    }
    cur = cur + 1; if (cur == 3) cur = 0;
  }
#undef OSTAGE

  const float* rb = res + (size_t)bz * 512 * 1024;
  float* Cb = Cf + (size_t)bz * 512 * 1024;
#pragma unroll
  for (int i = 0; i < 2; ++i) {
    int ob = m0 + wm * 32 + i * 16 + quad * 4;
#pragma unroll
    for (int r = 0; r < 4; ++r) {
      int o = ob + r;
      float bi = bias[o];
#pragma unroll
      for (int j = 0; j < 4; ++j) {
        int n = n0 + wn * 64 + j * 16 + lan15;
        Cb[(size_t)o * 1024 + n] = acc[i][j][r] + bi + rb[(size_t)o * 1024 + n];
      }
    }
  }
}

// ---------------------------------------------------------------------------
// MFMA flash attention v4 (verified): S^T-form QK (swapped MFMA operands),
// fixed-max exp2 softmax, b64-packed P stores, per-lane l.
// Block = 4 waves x 32 t; grid (64 bh, 8). K/V double-buffered, 1 barrier.
// Output attnT now written in K-blocked swizzled layout [16][1024][32].
// ---------------------------------------------------------------------------
#define AOFF_K 0           // 2 x 8192
#define AOFF_V 16384       // 2 x 8192
#define AOFF_P 32768       // 4 waves x 4608 (Q overlay + P [32][72])
#define AOFF_AM 51200      // 128 f32 (mask, then reused for l-sums)
#define ASMEM  51712

__global__ __launch_bounds__(256) void attn_kernel(
    const u16* __restrict__ Qh, const u16* __restrict__ Kf,
    const u16* __restrict__ Vf, const int* __restrict__ mask,
    u16* __restrict__ attnT) {
  __shared__ __align__(16) unsigned char smem[ASMEM];
  float* AM = (float*)(smem + AOFF_AM);

  int bh = blockIdx.x, b = bh >> 3, h = bh & 7;
  int t0 = blockIdx.y * 128;
  int tid = threadIdx.x;
  int lane = tid & 63, w = tid >> 6;
  int lan15 = lane & 15, quad = lane >> 4;
  int r8 = lane >> 3, c8 = lane & 7;
  int swE = (c8 ^ r8) * 8;

  const u16* Qb = Qh + (size_t)bh * 1024 * 64;
  const u16* Kb = Kf + (size_t)bh * 1152 * 64;
  const u16* Vb = Vf + (size_t)bh * 64 * 1152;
  char* Pw = (char*)smem + AOFF_P + w * 4608;
  u16* Pu = (u16*)Pw;

  if (tid < 128)
    AM[tid] = (tid < SS) ? ((mask[h * SS + tid] != 0) ? 0.f : MASKNEG) : -1e30f;

  // stage Q (wave-private region, overwritten by P later) + chunk 0 K/V
#pragma unroll
  for (int i = 0; i < 4; ++i)
    gl_lds16(Qb + (size_t)(t0 + w * 32 + i * 8 + r8) * 64 + swE, Pw + i * 1024);
#pragma unroll
  for (int i = 0; i < 2; ++i) {
    int row = w * 16 + i * 8;
    gl_lds16(Kb + (size_t)(row + r8) * 64 + swE, (char*)smem + AOFF_K + row * 128);
    gl_lds16(Vb + (size_t)(row + r8) * 1152 + swE, (char*)smem + AOFF_V + row * 128);
  }
  __syncthreads();

  // hoist Q fragments (used as MFMA B-operand: B[k=ch][n=t], t=lan15)
  v8s aq[2][2];
#pragma unroll
  for (int mt = 0; mt < 2; ++mt)
#pragma unroll
    for (int ks = 0; ks < 2; ++ks)
      aq[mt][ks] = *(const v8s*)(Pw + (mt * 16 + lan15) * 128 +
                                 (((ks * 4 + quad) ^ (lan15 & 7)) * 16));

  v4f O[2][4] = {};
  float lsum[2] = {0.f, 0.f};   // per-lane: all 16 chunk values share t=lan15

  for (int c = 0; c < 18; ++c) {
    int cur = c & 1;
    if (c < 17) {
      int nb = cur ^ 1;
#pragma unroll
      for (int i = 0; i < 2; ++i) {
        int row = w * 16 + i * 8;
        gl_lds16(Kb + (size_t)((c + 1) * 64 + row + r8) * 64 + swE,
                 (char*)smem + AOFF_K + nb * 8192 + row * 128);
        gl_lds16(Vb + (size_t)(row + r8) * 1152 + (c + 1) * 64 + swE,
                 (char*)smem + AOFF_V + nb * 8192 + row * 128);
      }
    }
    const char* Kc = (const char*)smem + AOFF_K + cur * 8192;
    const char* Vc = (const char*)smem + AOFF_V + cur * 8192;

    // QK^T transposed: ST[nt][mt], rows = s (quad*4+r), cols = t (lan15)
    v4f ST[4][2] = {};
#pragma unroll
    for (int ks = 0; ks < 2; ++ks) {
      int cofs = ((ks * 4 + quad) ^ (lan15 & 7)) * 16;
      v8s bk[4];
#pragma unroll
      for (int nt = 0; nt < 4; ++nt)
        bk[nt] = *(const v8s*)(Kc + (nt * 16 + lan15) * 128 + cofs);
#pragma unroll
      for (int nt = 0; nt < 4; ++nt)
#pragma unroll
        for (int mt = 0; mt < 2; ++mt)
          ST[nt][mt] = __builtin_amdgcn_mfma_f32_16x16x32_bf16(bk[nt], aq[mt][ks], ST[nt][mt], 0, 0, 0);
    }

    // mask add (enc chunks only): s = c*64 + nt*16 + quad*4 + r
    if (c < 2) {
#pragma unroll
      for (int nt = 0; nt < 4; ++nt)
#pragma unroll
        for (int r = 0; r < 4; ++r) {
          float a_ = AM[c * 64 + nt * 16 + quad * 4 + r];
#pragma unroll
          for (int mt = 0; mt < 2; ++mt) ST[nt][mt][r] += a_;
        }
    }

    // exp2 + b64-packed P store: Pu[(t)*72 + nt*16 + quad*4] = {e0..e3}
#pragma unroll
    for (int mt = 0; mt < 2; ++mt) {
#pragma unroll
      for (int nt = 0; nt < 4; ++nt) {
        float e0 = __builtin_amdgcn_exp2f(ST[nt][mt][0]);
        float e1 = __builtin_amdgcn_exp2f(ST[nt][mt][1]);
        float e2 = __builtin_amdgcn_exp2f(ST[nt][mt][2]);
        float e3 = __builtin_amdgcn_exp2f(ST[nt][mt][3]);
        u16x4 pk; pk.x = hi16(e0); pk.y = hi16(e1); pk.z = hi16(e2); pk.w = hi16(e3);
        *(u16x4*)&Pu[(mt * 16 + lan15) * 72 + nt * 16 + quad * 4] = pk;
        lsum[mt] += (e0 + e1) + (e2 + e3);
      }
    }

    // PV: O[t][c] += P[t][s] V^T[s][c]
#pragma unroll
    for (int ks = 0; ks < 2; ++ks) {
      int cofs = ((ks * 4 + quad) ^ (lan15 & 7)) * 16;
      v8s ap[2], bv[4];
#pragma unroll
      for (int mt = 0; mt < 2; ++mt)
        ap[mt] = *(const v8s*)(Pw + (mt * 16 + lan15) * 144 + ks * 64 + quad * 16);
#pragma unroll
      for (int nc = 0; nc < 4; ++nc)
        bv[nc] = *(const v8s*)(Vc + (nc * 16 + lan15) * 128 + cofs);
#pragma unroll
      for (int mt = 0; mt < 2; ++mt)
#pragma unroll
        for (int nc = 0; nc < 4; ++nc)
          O[mt][nc] = __builtin_amdgcn_mfma_f32_16x16x32_bf16(ap[mt], bv[nc], O[mt][nc], 0, 0, 0);
    }
    __syncthreads();
  }

  // l: reduce across quads (t=lan15), bounce through LDS to (quad*4+r) index
#pragma unroll
  for (int mt = 0; mt < 2; ++mt) {
    float v = lsum[mt];
    v += __shfl_xor(v, 16, 64);
    v += __shfl_xor(v, 32, 64);
    AM[w * 32 + mt * 16 + lan15] = v;   // 4 quads write identical value
  }
  __syncthreads();
  float inv[2][4];
#pragma unroll
  for (int mt = 0; mt < 2; ++mt)
#pragma unroll
    for (int r = 0; r < 4; ++r)
      inv[mt][r] = 1.0f / AM[w * 32 + mt * 16 + quad * 4 + r];

  float* Ot = (float*)smem;
#pragma unroll
  for (int mt = 0; mt < 2; ++mt)
#pragma unroll
    for (int nc = 0; nc < 4; ++nc)
#pragma unroll
      for (int r = 0; r < 4; ++r)
        Ot[(w * 32 + mt * 16 + quad * 4 + r) * 68 + nc * 16 + lan15] =
            O[mt][nc][r] * inv[mt][r];
  __syncthreads();
  {
    int row = tid >> 1, ks2 = tid & 1;
    const float* src = Ot + row * 68 + ks2 * 32;
    // dest: attnT[b][kstep = h*2+ks2][t0+row][chunk g ^ FR(row)]
    int frt = FR(row);   // t0 is a multiple of 128 -> FR(t0+row)=FR(row)
    u16* dpn = attnT + (((size_t)b * 16 + h * 2 + ks2) * 1024 + t0 + row) * 32;
#pragma unroll
    for (int g = 0; g < 4; ++g) {
      u16x8 o;
#pragma unroll
      for (int k = 0; k < 8; ++k) o[k] = f2bf(src[g * 8 + k]);
      *(u16x8*)(dpn + ((g ^ frt) * 8)) = o;
    }
  }
}

// ---------------------------------------------------------------------------
extern "C" void kernel_launch(void* const* d_in, const int* in_sizes, int n_in,
                              void* d_out, int out_size, void* d_ws, size_t ws_size,
                              hipStream_t stream) {
  const float* x       = (const float*)d_in[0];
  const float* enc     = (const float*)d_in[1];
  const int*   mask    = (const int*)d_in[2];
  const float* nscale  = (const float*)d_in[3];
  const float* nbias   = (const float*)d_in[4];
  const float* qkv_w   = (const float*)d_in[5];
  const float* qkv_b   = (const float*)d_in[6];
  const float* ekv_w   = (const float*)d_in[7];
  const float* ekv_b   = (const float*)d_in[8];
  const float* proj_w  = (const float*)d_in[9];
  const float* proj_b  = (const float*)d_in[10];
  float* out = (float*)d_out;

  char* ws = (char*)d_ws;
  const size_t MiB = 1048576;
  u16* nrmT   = (u16*)(ws);                        // 8 MiB  [8][16][1024][32]
  u16* Qh     = (u16*)(ws + 8 * MiB);              // 8 MiB  [64][1024][64]
  u16* Kfull  = (u16*)(ws + 16 * MiB);             // 9.4 MiB [64][1152][64]
  u16* Vfull  = (u16*)(ws + 26 * MiB);             // 9.4 MiB [64][64][1152]
  u16* attnT  = (u16*)(ws + 36 * MiB);             // 8 MiB  [8][16][1024][32]
  u16* encT   = (u16*)(ws + 44 * MiB);             // 1 MiB  [8][16][128][32]
  u16* wQK    = (u16*)(ws + 45 * MiB);             // 1 MiB  [16][1024][32]
  u16* wV     = (u16*)(ws + 46 * MiB);             // 0.5 MiB [16][512][32]
  u16* wEK    = (u16*)(ws + 46 * MiB + 524288);
  u16* wEV    = (u16*)(ws + 47 * MiB);
  u16* projwb = (u16*)(ws + 47 * MiB + 524288);
  float* bQK  = (float*)(ws + 48 * MiB);
  float* bV   = (float*)(ws + 48 * MiB + 4096);
  float* bEK  = (float*)(ws + 48 * MiB + 6144);
  float* bEV  = (float*)(ws + 48 * MiB + 8192);

  // 1) fused GroupNorm + prep
  prep_gn_kernel<<<dim3(2305), dim3(256), 0, stream>>>(
      x, nscale, nbias, nrmT, qkv_w, ekv_w, proj_w, enc, qkv_b, ekv_b,
      wQK, wV, wEK, wEV, projwb, encT, bQK, bV, bEK, bEV);

  // 2) ALL projections (QK + EK + V + EV) in one launch
  proj_all<<<dim3(104, BB), dim3(256), 0, stream>>>(
      nrmT, encT, wQK, wEK, wV, wEV, bQK, bEK, bV, bEV, Qh, Kfull, Vfull);

  // 3) attention -> attnT [8][16][1024][32]
  attn_kernel<<<dim3(64, 8), dim3(256), 0, stream>>>(
      Qh, Kfull, Vfull, mask, attnT);

  // 4) out = x + proj_w @ attn (64x128 tiles, 512 blocks = 2/CU)
  proj_out<<<dim3(8, 8, BB), dim3(256), 0, stream>>>(
      projwb, attnT, proj_b, x, out);
}